// Round 7
// baseline (114.678 us; speedup 1.0000x reference)
//
#include <hip/hip_runtime.h>
#include <stdint.h>

#define BB 8
#define LLEN 16384
#define CC 64
#define TOUT 8186
#define TILE_T 64
#define NROWS 140           // 2*TILE_T + 12 halo rows
#define NPAIR 70            // row pairs in slab
#define SXPS 68             // u32 per pair-row (272B)
#define SXGS 68             // shorts per gate row (136B)
#define YNS 66              // fp32 words per yn row
#define YNBS 76             // shorts per yn bf16 row

typedef __attribute__((ext_vector_type(8))) short short8;
typedef __attribute__((ext_vector_type(4))) float float4v;
typedef __attribute__((ext_vector_type(4))) unsigned int uint4v;
typedef __attribute__((ext_vector_type(4))) unsigned short ushort4v;

__device__ inline unsigned short f2bf(float f) {
  union { float f; uint32_t u; } v; v.f = f;
  uint32_t r = v.u + 0x7fffu + ((v.u >> 16) & 1u);
  return (unsigned short)(r >> 16);
}
__device__ inline float rcp_fast(float x) {
  float r; asm("v_rcp_f32 %0, %1" : "=v"(r) : "v"(x)); return r;
}
__device__ inline float tanh_fast(float a) {
  float e = __expf(2.0f * a);
  return 1.0f - 2.0f * rcp_fast(e + 1.0f);      // saturates at +/-1
}
__device__ inline void gload_lds16(const void* g, void* l) {
  __builtin_amdgcn_global_load_lds(
      (const __attribute__((address_space(1))) void*)g,
      (__attribute__((address_space(3))) void*)l, 16, 0, 0);
}

// Pack fp32 weights (C,C,K) -> bf16 MFMA B-frags (slab (kk*4+dq)*2+kh), and
// fp32 conv_kernel (C,C) -> bf16 B-frags (slab nt*2+kh, n = o).
__global__ void prep_frags(const float* __restrict__ weights,
                           const float* __restrict__ ck,
                           unsigned short* __restrict__ wfrag,
                           unsigned short* __restrict__ ckfrag)
{
  int bid = blockIdx.x, tid = threadIdx.x;
  if (bid < 56) {
    int nt = bid >> 1, kh = bid & 1;
    for (int e = tid; e < 512; e += 256) {
      int ln = e >> 3, j = e & 7;
      int kk = nt >> 2;                 // nt = kk*4 + dq
      int d  = (nt & 3) * 16 + (ln & 15);
      int cp = kh * 32 + (ln >> 4) * 8 + j;
      wfrag[(bid * 64 + ln) * 8 + j] = f2bf(weights[d * 448 + cp * 7 + kk]);
    }
  } else {
    int bb2 = bid - 56;
    int nt = bb2 >> 1, kh = bb2 & 1;
    for (int e = tid; e < 512; e += 256) {
      int ln = e >> 3, j = e & 7;
      int oo = nt * 16 + (ln & 15);
      int c2 = kh * 32 + (ln >> 4) * 8 + j;
      ckfrag[(bb2 * 64 + ln) * 8 + j] = f2bf(ck[c2 * 64 + oo]);
    }
  }
}

__global__ __launch_bounds__(256, 3)
void convblock_main(const float* __restrict__ x,
                    const unsigned short* __restrict__ wfrag,
                    const unsigned short* __restrict__ ckfrag,
                    const float* __restrict__ ln_scale,
                    const float* __restrict__ ln_bias,
                    const float* __restrict__ conv_bias,
                    const float* __restrict__ prelu_slope,
                    float* __restrict__ out)
{
  __shared__ __align__(16) char smem[52832];
  uint32_t*       sxp  = (uint32_t*)smem;                 // [0,19040): packed bf16 pairs, swizzled
  unsigned short* sxg  = (unsigned short*)(smem + 19040); // [19040,36448): gate rows bf16
  unsigned short* wbuf = (unsigned short*)(smem + 36448); // [36448,52832): 2 x 8KB B-frag buffers
  float*          ynf  = (float*)(smem + 19040);          // overlay sxg (16896 B)
  unsigned short* ynb  = (unsigned short*)smem;           // overlay sxp (9728 B)

  const int tid  = threadIdx.x;
  const int b    = blockIdx.x >> 7;              // 128 tiles per batch
  const int t0   = (blockIdx.x & 127) * TILE_T;
  const int lane = tid & 63;
  const int w    = tid >> 6;
  const int l15  = tid & 15;
  const int q    = (tid >> 4) & 3;

  // prefetch kk=0 B-frags into wbuf[0]: wave w stages its dq=w slice
  {
    const char* s0 = (const char*)wfrag + ((((0 * 4 + w) * 2 + 0) * 64 + lane) << 4);
    const char* s1 = (const char*)wfrag + ((((0 * 4 + w) * 2 + 1) * 64 + lane) << 4);
    gload_lds16(s0, (char*)wbuf + (w * 2 + 0) * 1024);
    gload_lds16(s1, (char*)wbuf + (w * 2 + 1) * 1024);
  }

  // ---- phase 1: stage x slab rows 2t0..2t0+139 as bf16 (pairs + gate rows) ----
  {
    const float* xb = x + (size_t)b * ((size_t)LLEN * CC);
    #pragma unroll
    for (int i = 0; i < 5; ++i) {
      int u = tid + i * 256;
      if (u < NPAIR * 16) {
        int rp = u >> 4, f4 = u & 15, c0 = f4 * 4;
        int g0 = 2 * t0 + 2 * rp, g1 = g0 + 1;
        if (g0 > LLEN - 1) g0 = LLEN - 1;        // only feeds t >= TOUT (never stored)
        if (g1 > LLEN - 1) g1 = LLEN - 1;
        float4v ve = *(const float4v*)(xb + (size_t)g0 * CC + c0);
        float4v vo = *(const float4v*)(xb + (size_t)g1 * CC + c0);
        ushort4v pe, po;
        #pragma unroll
        for (int j = 0; j < 4; ++j) { pe[j] = f2bf(ve[j]); po[j] = f2bf(vo[j]); }
        int sw = rp & 7;
        #pragma unroll
        for (int j = 0; j < 4; ++j) {
          int c = c0 + j;
          sxp[rp * SXPS + (((c & 15) ^ sw) << 2) + (c >> 4)] =
              (uint32_t)pe[j] | ((uint32_t)po[j] << 16);
        }
        int r0 = 2 * rp, r1 = 2 * rp + 1;
        if (r0 >= 12) *(ushort4v*)&sxg[(r0 - 12) * SXGS + c0] = pe;
        if (r1 >= 12) *(ushort4v*)&sxg[(r1 - 12) * SXGS + c0] = po;
      }
    }
  }
  float lnS[4], lnB[4];
  #pragma unroll
  for (int dq = 0; dq < 4; ++dq) {
    lnS[dq] = ln_scale[16 * dq + l15];
    lnB[dq] = ln_bias[16 * dq + l15];
  }
  __syncthreads();                               // slab + kk=0 B-frags ready

  // A-fragments: wave w owns ptiles {w, w+4} (gate rows 16w.., 64+16w..)
  short8 a0 = *(const short8*)&sxg[(16 * w + l15) * SXGS + q * 8];
  short8 a1 = *(const short8*)&sxg[(16 * w + l15) * SXGS + 32 + q * 8];
  short8 a2 = *(const short8*)&sxg[(64 + 16 * w + l15) * SXGS + q * 8];
  short8 a3 = *(const short8*)&sxg[(64 + 16 * w + l15) * SXGS + 32 + q * 8];

  // ---- phase 2+3: per-kk staged MFMA -> tanh -> y ----
  float y[2][2][4];
  #pragma unroll
  for (int ph = 0; ph < 2; ++ph)
    #pragma unroll
    for (int dlt = 0; dlt < 2; ++dlt)
      #pragma unroll
      for (int dq = 0; dq < 4; ++dq) y[ph][dlt][dq] = 0.f;

  const int tb = 8 * w + 2 * q;
  #pragma unroll
  for (int kk = 0; kk < 7; ++kk) {
    if (kk < 6) {                                // prefetch kk+1 into other buffer
      const char* s0 = (const char*)wfrag + (((((kk + 1) * 4 + w) * 2 + 0) * 64 + lane) << 4);
      const char* s1 = (const char*)wfrag + (((((kk + 1) * 4 + w) * 2 + 1) * 64 + lane) << 4);
      char* db = (char*)wbuf + ((kk + 1) & 1) * 8192;
      gload_lds16(s0, db + (w * 2 + 0) * 1024);
      gload_lds16(s1, db + (w * 2 + 1) * 1024);
    }
    const unsigned short* wb = wbuf + (kk & 1) * 4096;
    float4v acc[2][4];
    #pragma unroll
    for (int dq = 0; dq < 4; ++dq) {
      short8 b0 = *(const short8*)&wb[((dq * 2 + 0) * 64 + lane) * 8];
      short8 b1 = *(const short8*)&wb[((dq * 2 + 1) * 64 + lane) * 8];
      float4v u0 = (float4v){0.f, 0.f, 0.f, 0.f};
      float4v u1 = (float4v){0.f, 0.f, 0.f, 0.f};
      u0 = __builtin_amdgcn_mfma_f32_16x16x32_bf16(a0, b0, u0, 0, 0, 0);
      u0 = __builtin_amdgcn_mfma_f32_16x16x32_bf16(a1, b1, u0, 0, 0, 0);
      u1 = __builtin_amdgcn_mfma_f32_16x16x32_bf16(a2, b0, u1, 0, 0, 0);
      u1 = __builtin_amdgcn_mfma_f32_16x16x32_bf16(a3, b1, u1, 0, 0, 0);
      acc[0][dq] = u0;
      acc[1][dq] = u1;
    }
    #pragma unroll
    for (int ph = 0; ph < 2; ++ph) {
      #pragma unroll
      for (int dlt = 0; dlt < 2; ++dlt) {
        int rp = ph * 32 + tb + dlt + kk;        // multiplier pair-row
        uint4v pr = *(const uint4v*)&sxp[rp * SXPS + ((l15 ^ (rp & 7)) << 2)];
        #pragma unroll
        for (int dq = 0; dq < 4; ++dq) {
          uint32_t u = pr[dq];
          float xe = __uint_as_float(u << 16);
          float xo = __uint_as_float(u & 0xffff0000u);
          float ge = tanh_fast(acc[ph][dq][2 * dlt + 0]);
          float go = tanh_fast(acc[ph][dq][2 * dlt + 1]);
          y[ph][dlt][dq] += xe * ge + xo * go;
          if (kk == 6) y[ph][dlt][dq] += xe;     // residual x[12+2t] (= kk=6 even row)
        }
      }
    }
    __syncthreads();                             // staged buf visible; reads drained
  }

  // ---- LayerNorm (registers + 16-lane shuffle), write ynf + ynb overlays ----
  #pragma unroll
  for (int ph = 0; ph < 2; ++ph) {
    #pragma unroll
    for (int dlt = 0; dlt < 2; ++dlt) {
      float s1 = y[ph][dlt][0] + y[ph][dlt][1] + y[ph][dlt][2] + y[ph][dlt][3];
      float s2 = y[ph][dlt][0]*y[ph][dlt][0] + y[ph][dlt][1]*y[ph][dlt][1]
               + y[ph][dlt][2]*y[ph][dlt][2] + y[ph][dlt][3]*y[ph][dlt][3];
      #pragma unroll
      for (int m = 1; m < 16; m <<= 1) {
        s1 += __shfl_xor(s1, m, 64);
        s2 += __shfl_xor(s2, m, 64);
      }
      float mu   = s1 * (1.0f / 64.0f);
      float var  = s2 * (1.0f / 64.0f) - mu * mu;
      float rstd = rsqrtf(var + 1e-6f);
      int tl = ph * 32 + tb + dlt;
      #pragma unroll
      for (int dq = 0; dq < 4; ++dq) {
        float yn = (y[ph][dlt][dq] - mu) * rstd * lnS[dq] + lnB[dq];
        ynf[tl * YNS + 16 * dq + l15] = yn;      // sxg overlay (sxg dead)
        ynb[tl * YNBS + 16 * dq + l15] = f2bf(yn); // sxp overlay (post-loop barrier)
      }
    }
  }
  __syncthreads();

  // ---- phase 4: z = yn @ ck + cb via MFMA, PReLU, out = yn + z (fp32) ----
  const float sl = prelu_slope[0];
  const int   o  = 16 * w + l15;                 // wave w owns o-tile w
  const float cb = conv_bias[o];
  short8 bf0 = *(const short8*)&ckfrag[((w * 2 + 0) * 64 + lane) * 8];
  short8 bf1 = *(const short8*)&ckfrag[((w * 2 + 1) * 64 + lane) * 8];
  #pragma unroll
  for (int mt = 0; mt < 4; ++mt) {
    short8 af0 = *(const short8*)&ynb[(mt * 16 + l15) * YNBS + q * 8];
    short8 af1 = *(const short8*)&ynb[(mt * 16 + l15) * YNBS + 32 + q * 8];
    float4v zc = (float4v){0.f, 0.f, 0.f, 0.f};
    zc = __builtin_amdgcn_mfma_f32_16x16x32_bf16(af0, bf0, zc, 0, 0, 0);
    zc = __builtin_amdgcn_mfma_f32_16x16x32_bf16(af1, bf1, zc, 0, 0, 0);
    #pragma unroll
    for (int r = 0; r < 4; ++r) {
      int t  = mt * 16 + 4 * q + r;
      int tg = t0 + t;
      if (tg < TOUT) {
        float z = zc[r] + cb;
        z = (z >= 0.f) ? z : sl * z;
        out[((size_t)b * TOUT + tg) * CC + o] = ynf[t * YNS + o] + z;
      }
    }
  }
}

extern "C" void kernel_launch(void* const* d_in, const int* in_sizes, int n_in,
                              void* d_out, int out_size, void* d_ws, size_t ws_size,
                              hipStream_t stream)
{
  const float* x        = (const float*)d_in[0];
  const float* weights  = (const float*)d_in[1];
  const float* ln_scale = (const float*)d_in[2];
  const float* ln_bias  = (const float*)d_in[3];
  const float* ck       = (const float*)d_in[4];
  const float* cb       = (const float*)d_in[5];
  const float* slope    = (const float*)d_in[6];
  unsigned short* wfrag  = (unsigned short*)d_ws;                  // 57344 B
  unsigned short* ckfrag = (unsigned short*)((char*)d_ws + 57344); // 8192 B

  prep_frags<<<64, 256, 0, stream>>>(weights, ck, wfrag, ckfrag);
  convblock_main<<<BB * 128, 256, 0, stream>>>(x, wfrag, ckfrag, ln_scale,
                                               ln_bias, cb, slope, (float*)d_out);
}